// Round 4
// baseline (184.439 us; speedup 1.0000x reference)
//
#include <hip/hip_runtime.h>
#include <math.h>

// CRPS reduction kernel for MI355X (gfx950), round 3 (resubmit — round-3 bench
// was lost to a GPU acquisition timeout, no counters were produced).
// Round-2 analysis: VALUBusy 37%, HBM 16%, occupancy 61% -> latency-bound,
// not enough ILP (VGPR=24, one dependency chain). This round: grid-stride
// unroll-by-4 with all loads hoisted (8 independent element chains, 12
// outstanding vector loads per wave).
//
//   d_in[0]: pred_params (B,2) f32  -> mu = [:,0], ls = [:,1] (sigma2 = exp(ls))
//   d_in[1]: tgts        (B,2) f32  -> tte = [:,0], censor = [:,1]
//   d_in[2]: ages        (B,)  f32
//   d_in[3]: use_intvl   int scalar (device)
// Output: d_out[0] = sum(crps)/B  (f32 scalar)

#define AGE_MAX_F      120.0f
#define INV_SQRT_PI_F  0.5641895835477563f
#define INV_SQRT_2PI_F 0.3989422804014327f
#define SQRT_2PI_F     2.5066282746310002f
#define SQRT_2_F       1.4142135623730951f

// Phi(z) given phi = standard normal pdf at z. Abramowitz-Stegun 26.2.17,
// |err| < 7.5e-8, fully branchless.
__device__ __forceinline__ float ndtr_from_pdf(float z, float phi) {
    const float za = fabsf(z);
    const float t  = __builtin_amdgcn_rcpf(fmaf(0.2316419f, za, 1.0f));
    float p = fmaf(1.330274429f, t, -1.821255978f);
    p = fmaf(p, t, 1.781477937f);
    p = fmaf(p, t, -0.356563782f);
    p = fmaf(p, t, 0.319381530f);
    p = p * t;
    const float hm = fmaf(-phi, p, 0.5f);          // Phi(|z|) - 0.5
    return fmaf(copysignf(1.0f, z), hm, 0.5f);     // Phi(z)
}

__device__ __forceinline__ float crps_elem(float mu, float ls, float tte,
                                           float cen, float age, int use_intvl) {
    const float s     = __expf( 0.5f * ls);   // sqrt(sigma2)
    const float inv_s = __expf(-0.5f * ls);   // 1/sqrt(sigma2)
    const float Y     = __logf(tte);

    const float dy   = Y - mu;
    const float z    = dy * inv_s;
    const float pdf  = __expf(-0.5f * z * z) * INV_SQRT_2PI_F;
    const float c    = ndtr_from_pdf(z, pdf);
    const float pdf2 = pdf * pdf * SQRT_2PI_F;      // phi(z*sqrt(2))
    const float c2   = ndtr_from_pdf(z * SQRT_2_F, pdf2);

    const float sp  = s * INV_SQRT_PI_F;
    const float IY  = dy * c * c + 2.0f * s * c * pdf - sp * c2;
    const float omc = 1.0f - c;
    const float InY = -dy * omc * omc + 2.0f * s * omc * pdf - sp * (1.0f - c2);

    if (use_intvl) {
        const float T     = __logf(AGE_MAX_F - age);
        const float dt    = mu - T;                 // argument of I_(-T)
        const float zt    = dt * inv_s;
        const float pdft  = __expf(-0.5f * zt * zt) * INV_SQRT_2PI_F;
        const float ct    = ndtr_from_pdf(zt, pdft);
        const float pdft2 = pdft * pdft * SQRT_2PI_F;
        const float c2t   = ndtr_from_pdf(zt * SQRT_2_F, pdft2);
        const float InT   = dt * ct * ct + 2.0f * s * ct * pdft - sp * c2t;
        return IY + InT + (1.0f - cen) * (InY - InT);
    } else {
        return IY + (1.0f - cen) * InY;
    }
}

__device__ __forceinline__ float crps_pair(float4 p, float4 t, float2 a, int ui) {
    return crps_elem(p.x, p.y, t.x, t.y, a.x, ui)
         + crps_elem(p.z, p.w, t.z, t.w, a.y, ui);
}

__global__ __launch_bounds__(256) void crps_kernel(
    const float4* __restrict__ pp,
    const float4* __restrict__ tg,
    const float2* __restrict__ ag,
    const int*    __restrict__ use_intvl_p,
    float*        __restrict__ out,
    int npairs, float inv_total)
{
    const int tid    = blockIdx.x * blockDim.x + threadIdx.x;
    const int stride = gridDim.x * blockDim.x;
    const int ui     = *use_intvl_p;

    float acc = 0.0f;

    int i = tid;
    // unroll-by-4: hoist all 12 vector loads, then 8 independent element chains
    for (; i + 3 * stride < npairs; i += 4 * stride) {
        const int i0 = i;
        const int i1 = i + stride;
        const int i2 = i + 2 * stride;
        const int i3 = i + 3 * stride;

        const float4 p0 = pp[i0]; const float4 p1 = pp[i1];
        const float4 p2 = pp[i2]; const float4 p3 = pp[i3];
        const float4 t0 = tg[i0]; const float4 t1 = tg[i1];
        const float4 t2 = tg[i2]; const float4 t3 = tg[i3];
        const float2 a0 = ag[i0]; const float2 a1 = ag[i1];
        const float2 a2 = ag[i2]; const float2 a3 = ag[i3];

        float s0 = crps_pair(p0, t0, a0, ui);
        float s1 = crps_pair(p1, t1, a1, ui);
        float s2 = crps_pair(p2, t2, a2, ui);
        float s3 = crps_pair(p3, t3, a3, ui);
        acc += (s0 + s1) + (s2 + s3);
    }
    for (; i < npairs; i += stride) {
        acc += crps_pair(pp[i], tg[i], ag[i], ui);
    }

    // wave64 shuffle reduce
    #pragma unroll
    for (int off = 32; off > 0; off >>= 1)
        acc += __shfl_down(acc, off);

    __shared__ float wsum[4];
    const int lane = threadIdx.x & 63;
    const int wid  = threadIdx.x >> 6;
    if (lane == 0) wsum[wid] = acc;
    __syncthreads();
    if (threadIdx.x == 0) {
        const float blocksum = wsum[0] + wsum[1] + wsum[2] + wsum[3];
        atomicAdd(out, blocksum * inv_total);
    }
}

extern "C" void kernel_launch(void* const* d_in, const int* in_sizes, int n_in,
                              void* d_out, int out_size, void* d_ws, size_t ws_size,
                              hipStream_t stream) {
    const float4* pp = (const float4*)d_in[0];
    const float4* tg = (const float4*)d_in[1];
    const float2* ag = (const float2*)d_in[2];
    const int*    ui = (const int*)d_in[3];
    float* out = (float*)d_out;

    const int n      = in_sizes[2];      // B
    const int npairs = n >> 1;
    const float inv_total = 1.0f / (float)n;

    hipMemsetAsync(d_out, 0, sizeof(float), stream);

    int blocks = (npairs + 255) / 256;
    if (blocks > 2048) blocks = 2048;
    crps_kernel<<<blocks, 256, 0, stream>>>(pp, tg, ag, ui, out, npairs, inv_total);
}

// Round 6
// 178.756 us; speedup vs baseline: 1.0318x; 1.0318x over previous
//
#include <hip/hip_runtime.h>
#include <math.h>

// CRPS reduction kernel for MI355X (gfx950), round 5 (resubmit — round-5 bench
// lost to GPU acquisition timeout, no counters produced).
// Round-4 post-mortem: unroll-by-4 was re-serialized by regalloc (VGPR stuck
// at 32, VALUBusy flat 37%). Round-2's zero-fetch dispatch ran same 71us ->
// not HBM-bound. This round:
//   (a) __launch_bounds__(256,4): grant 128 VGPR so the 8 element chains can
//       actually interleave (measured occupancy was ~4 waves/SIMD anyway);
//   (b) kill the 2048-way same-address atomicAdd tail (cross-XCD cacheline
//       ping-pong): block partials -> d_ws, then a tiny reduce kernel.
//
//   d_in[0]: pred_params (B,2) f32  -> mu = [:,0], ls = [:,1]
//   d_in[1]: tgts        (B,2) f32  -> tte = [:,0], censor = [:,1]
//   d_in[2]: ages        (B,)  f32
//   d_in[3]: use_intvl   int scalar (device)
// Output: d_out[0] = sum(crps)/B  (f32 scalar)

#define AGE_MAX_F      120.0f
#define INV_SQRT_PI_F  0.5641895835477563f
#define INV_SQRT_2PI_F 0.3989422804014327f
#define SQRT_2PI_F     2.5066282746310002f
#define SQRT_2_F       1.4142135623730951f

#define NBLOCKS 2048
#define NTHREADS 256

// Phi(z) given phi = standard normal pdf at z. Abramowitz-Stegun 26.2.17,
// |err| < 7.5e-8, fully branchless.
__device__ __forceinline__ float ndtr_from_pdf(float z, float phi) {
    const float za = fabsf(z);
    const float t  = __builtin_amdgcn_rcpf(fmaf(0.2316419f, za, 1.0f));
    float p = fmaf(1.330274429f, t, -1.821255978f);
    p = fmaf(p, t, 1.781477937f);
    p = fmaf(p, t, -0.356563782f);
    p = fmaf(p, t, 0.319381530f);
    p = p * t;
    const float hm = fmaf(-phi, p, 0.5f);          // Phi(|z|) - 0.5
    return fmaf(copysignf(1.0f, z), hm, 0.5f);     // Phi(z)
}

__device__ __forceinline__ float crps_elem(float mu, float ls, float tte,
                                           float cen, float age, int use_intvl) {
    const float s     = __expf( 0.5f * ls);   // sqrt(sigma2)
    const float inv_s = __expf(-0.5f * ls);   // 1/sqrt(sigma2)
    const float Y     = __logf(tte);

    const float dy   = Y - mu;
    const float z    = dy * inv_s;
    const float pdf  = __expf(-0.5f * z * z) * INV_SQRT_2PI_F;
    const float c    = ndtr_from_pdf(z, pdf);
    const float pdf2 = pdf * pdf * SQRT_2PI_F;      // phi(z*sqrt(2))
    const float c2   = ndtr_from_pdf(z * SQRT_2_F, pdf2);

    const float sp  = s * INV_SQRT_PI_F;
    const float tp  = 2.0f * s * pdf;               // shared by IY/InY
    const float IY  = dy * c * c + tp * c - sp * c2;
    const float omc = 1.0f - c;
    const float InY = -dy * omc * omc + tp * omc - sp * (1.0f - c2);

    if (use_intvl) {
        const float T     = __logf(AGE_MAX_F - age);
        const float dt    = mu - T;                 // argument of I_(-T)
        const float zt    = dt * inv_s;
        const float pdft  = __expf(-0.5f * zt * zt) * INV_SQRT_2PI_F;
        const float ct    = ndtr_from_pdf(zt, pdft);
        const float pdft2 = pdft * pdft * SQRT_2PI_F;
        const float c2t   = ndtr_from_pdf(zt * SQRT_2_F, pdft2);
        const float InT   = dt * ct * ct + 2.0f * s * ct * pdft - sp * c2t;
        return IY + InT + (1.0f - cen) * (InY - InT);
    } else {
        return IY + (1.0f - cen) * InY;
    }
}

__device__ __forceinline__ float crps_pair(float4 p, float4 t, float2 a, int ui) {
    return crps_elem(p.x, p.y, t.x, t.y, a.x, ui)
         + crps_elem(p.z, p.w, t.z, t.w, a.y, ui);
}

template <bool USE_ATOMIC>
__global__ __launch_bounds__(NTHREADS, 4) void crps_kernel(
    const float4* __restrict__ pp,
    const float4* __restrict__ tg,
    const float2* __restrict__ ag,
    const int*    __restrict__ use_intvl_p,
    float*        __restrict__ partials,   // NBLOCKS floats (or d_out if atomic)
    int npairs, float inv_total)
{
    const int tid    = blockIdx.x * blockDim.x + threadIdx.x;
    const int stride = gridDim.x * blockDim.x;
    const int ui     = *use_intvl_p;

    float acc = 0.0f;

    int i = tid;
    for (; i + 3 * stride < npairs; i += 4 * stride) {
        float4 p[4], t[4];
        float2 a[4];
        #pragma unroll
        for (int u = 0; u < 4; ++u) {
            const int idx = i + u * stride;
            p[u] = pp[idx];
            t[u] = tg[idx];
            a[u] = ag[idx];
        }
        float s0 = crps_pair(p[0], t[0], a[0], ui);
        float s1 = crps_pair(p[1], t[1], a[1], ui);
        float s2 = crps_pair(p[2], t[2], a[2], ui);
        float s3 = crps_pair(p[3], t[3], a[3], ui);
        acc += (s0 + s1) + (s2 + s3);
    }
    for (; i < npairs; i += stride) {
        acc += crps_pair(pp[i], tg[i], ag[i], ui);
    }

    // wave64 shuffle reduce
    #pragma unroll
    for (int off = 32; off > 0; off >>= 1)
        acc += __shfl_down(acc, off);

    __shared__ float wsum[NTHREADS / 64];
    const int lane = threadIdx.x & 63;
    const int wid  = threadIdx.x >> 6;
    if (lane == 0) wsum[wid] = acc;
    __syncthreads();
    if (threadIdx.x == 0) {
        float blocksum = 0.0f;
        #pragma unroll
        for (int w = 0; w < NTHREADS / 64; ++w) blocksum += wsum[w];
        if (USE_ATOMIC) {
            atomicAdd(partials, blocksum * inv_total);
        } else {
            partials[blockIdx.x] = blocksum;
        }
    }
}

// Reduce NBLOCKS partials -> out[0] = sum * inv_total. One block.
__global__ __launch_bounds__(256) void reduce_kernel(
    const float4* __restrict__ partials,  // NBLOCKS/4 float4s
    float* __restrict__ out, float inv_total)
{
    float acc = 0.0f;
    // NBLOCKS/4 = 512 float4s; 256 threads x 2
    #pragma unroll
    for (int u = 0; u < 2; ++u) {
        const float4 v = partials[threadIdx.x + u * 256];
        acc += (v.x + v.y) + (v.z + v.w);
    }
    #pragma unroll
    for (int off = 32; off > 0; off >>= 1)
        acc += __shfl_down(acc, off);

    __shared__ float wsum[4];
    const int lane = threadIdx.x & 63;
    const int wid  = threadIdx.x >> 6;
    if (lane == 0) wsum[wid] = acc;
    __syncthreads();
    if (threadIdx.x == 0) {
        out[0] = ((wsum[0] + wsum[1]) + (wsum[2] + wsum[3])) * inv_total;
    }
}

extern "C" void kernel_launch(void* const* d_in, const int* in_sizes, int n_in,
                              void* d_out, int out_size, void* d_ws, size_t ws_size,
                              hipStream_t stream) {
    const float4* pp = (const float4*)d_in[0];
    const float4* tg = (const float4*)d_in[1];
    const float2* ag = (const float2*)d_in[2];
    const int*    ui = (const int*)d_in[3];
    float* out = (float*)d_out;

    const int n      = in_sizes[2];      // B
    const int npairs = n >> 1;
    const float inv_total = 1.0f / (float)n;

    if (ws_size >= NBLOCKS * sizeof(float)) {
        float* partials = (float*)d_ws;
        crps_kernel<false><<<NBLOCKS, NTHREADS, 0, stream>>>(
            pp, tg, ag, ui, partials, npairs, inv_total);
        reduce_kernel<<<1, 256, 0, stream>>>(
            (const float4*)partials, out, inv_total);
    } else {
        // fallback: single-kernel atomic path
        hipMemsetAsync(d_out, 0, sizeof(float), stream);
        crps_kernel<true><<<NBLOCKS, NTHREADS, 0, stream>>>(
            pp, tg, ag, ui, out, npairs, inv_total);
    }
}

// Round 7
// 176.029 us; speedup vs baseline: 1.0478x; 1.0155x over previous
//
#include <hip/hip_runtime.h>
#include <math.h>

// CRPS reduction kernel for MI355X (gfx950), round 7.
// Round-6 post-mortem: launch_bounds(256,4) did NOT raise VGPR (still 32);
// compiler re-serializes source-level unrolling and sinks loads to the use
// point -> exposed latency, VALUBusy stuck ~36%, dur ~68us (5x the ~13us
// issue floor). This round: structural TLP/MLP instead of in-thread ILP:
// NO grid-stride loop. 8192 blocks x 256 threads, exactly 2 pairs per
// thread, all 6 vector loads issued at wave start, straight-line body.
// Every load in the kernel is independent; 32 waves/CU hide trans + mem
// latency by wave switching.
//
//   d_in[0]: pred_params (B,2) f32  -> mu = [:,0], ls = [:,1]
//   d_in[1]: tgts        (B,2) f32  -> tte = [:,0], censor = [:,1]
//   d_in[2]: ages        (B,)  f32
//   d_in[3]: use_intvl   int scalar (device)
// Output: d_out[0] = sum(crps)/B  (f32 scalar)

#define AGE_MAX_F      120.0f
#define INV_SQRT_PI_F  0.5641895835477563f
#define INV_SQRT_2PI_F 0.3989422804014327f
#define SQRT_2PI_F     2.5066282746310002f
#define SQRT_2_F       1.4142135623730951f

#define NTHREADS 256

// Phi(z) given phi = standard normal pdf at z. Abramowitz-Stegun 26.2.17,
// |err| < 7.5e-8, fully branchless.
__device__ __forceinline__ float ndtr_from_pdf(float z, float phi) {
    const float za = fabsf(z);
    const float t  = __builtin_amdgcn_rcpf(fmaf(0.2316419f, za, 1.0f));
    float p = fmaf(1.330274429f, t, -1.821255978f);
    p = fmaf(p, t, 1.781477937f);
    p = fmaf(p, t, -0.356563782f);
    p = fmaf(p, t, 0.319381530f);
    p = p * t;
    const float hm = fmaf(-phi, p, 0.5f);          // Phi(|z|) - 0.5
    return fmaf(copysignf(1.0f, z), hm, 0.5f);     // Phi(z)
}

__device__ __forceinline__ float crps_elem(float mu, float ls, float tte,
                                           float cen, float age, int use_intvl) {
    const float s     = __expf( 0.5f * ls);   // sqrt(sigma2)
    const float inv_s = __expf(-0.5f * ls);   // 1/sqrt(sigma2)
    const float Y     = __logf(tte);

    const float dy   = Y - mu;
    const float z    = dy * inv_s;
    const float pdf  = __expf(-0.5f * z * z) * INV_SQRT_2PI_F;
    const float c    = ndtr_from_pdf(z, pdf);
    const float pdf2 = pdf * pdf * SQRT_2PI_F;      // phi(z*sqrt(2))
    const float c2   = ndtr_from_pdf(z * SQRT_2_F, pdf2);

    const float sp  = s * INV_SQRT_PI_F;
    const float tp  = 2.0f * s * pdf;               // shared by IY/InY
    const float IY  = dy * c * c + tp * c - sp * c2;
    const float omc = 1.0f - c;
    const float InY = -dy * omc * omc + tp * omc - sp * (1.0f - c2);

    if (use_intvl) {
        const float T     = __logf(AGE_MAX_F - age);
        const float dt    = mu - T;                 // argument of I_(-T)
        const float zt    = dt * inv_s;
        const float pdft  = __expf(-0.5f * zt * zt) * INV_SQRT_2PI_F;
        const float ct    = ndtr_from_pdf(zt, pdft);
        const float pdft2 = pdft * pdft * SQRT_2PI_F;
        const float c2t   = ndtr_from_pdf(zt * SQRT_2_F, pdft2);
        const float InT   = dt * ct * ct + 2.0f * s * ct * pdft - sp * c2t;
        return IY + InT + (1.0f - cen) * (InY - InT);
    } else {
        return IY + (1.0f - cen) * InY;
    }
}

__device__ __forceinline__ float crps_pair(float4 p, float4 t, float2 a, int ui) {
    return crps_elem(p.x, p.y, t.x, t.y, a.x, ui)
         + crps_elem(p.z, p.w, t.z, t.w, a.y, ui);
}

template <bool USE_ATOMIC>
__global__ __launch_bounds__(NTHREADS) void crps_kernel(
    const float4* __restrict__ pp,
    const float4* __restrict__ tg,
    const float2* __restrict__ ag,
    const int*    __restrict__ use_intvl_p,
    float*        __restrict__ partials,   // one float per block (or d_out if atomic)
    int npairs, float inv_total)
{
    const int half = gridDim.x * NTHREADS;          // pairs handled in slot 0
    const int i0   = blockIdx.x * NTHREADS + threadIdx.x;
    const int i1   = i0 + half;
    const int ui   = *use_intvl_p;

    // Straight-line: both pairs' loads issue before any compute.
    float acc = 0.0f;
    if (i0 < npairs) {
        const float4 p0 = pp[i0];
        const float4 t0 = tg[i0];
        const float2 a0 = ag[i0];
        if (i1 < npairs) {
            const float4 p1 = pp[i1];
            const float4 t1 = tg[i1];
            const float2 a1 = ag[i1];
            acc = crps_pair(p0, t0, a0, ui) + crps_pair(p1, t1, a1, ui);
        } else {
            acc = crps_pair(p0, t0, a0, ui);
        }
    }

    // wave64 shuffle reduce
    #pragma unroll
    for (int off = 32; off > 0; off >>= 1)
        acc += __shfl_down(acc, off);

    __shared__ float wsum[NTHREADS / 64];
    const int lane = threadIdx.x & 63;
    const int wid  = threadIdx.x >> 6;
    if (lane == 0) wsum[wid] = acc;
    __syncthreads();
    if (threadIdx.x == 0) {
        float blocksum = 0.0f;
        #pragma unroll
        for (int w = 0; w < NTHREADS / 64; ++w) blocksum += wsum[w];
        if (USE_ATOMIC) {
            atomicAdd(partials, blocksum * inv_total);
        } else {
            partials[blockIdx.x] = blocksum;
        }
    }
}

// Reduce nparts partials -> out[0] = sum * inv_total. One block of 1024.
__global__ __launch_bounds__(1024) void reduce_kernel(
    const float* __restrict__ partials,
    float* __restrict__ out, int nparts, float inv_total)
{
    float acc = 0.0f;
    for (int i = threadIdx.x; i < nparts; i += 1024)
        acc += partials[i];

    #pragma unroll
    for (int off = 32; off > 0; off >>= 1)
        acc += __shfl_down(acc, off);

    __shared__ float wsum[16];
    const int lane = threadIdx.x & 63;
    const int wid  = threadIdx.x >> 6;
    if (lane == 0) wsum[wid] = acc;
    __syncthreads();
    if (threadIdx.x == 0) {
        float s = 0.0f;
        #pragma unroll
        for (int w = 0; w < 16; ++w) s += wsum[w];
        out[0] = s * inv_total;
    }
}

extern "C" void kernel_launch(void* const* d_in, const int* in_sizes, int n_in,
                              void* d_out, int out_size, void* d_ws, size_t ws_size,
                              hipStream_t stream) {
    const float4* pp = (const float4*)d_in[0];
    const float4* tg = (const float4*)d_in[1];
    const float2* ag = (const float2*)d_in[2];
    const int*    ui = (const int*)d_in[3];
    float* out = (float*)d_out;

    const int n      = in_sizes[2];      // B
    const int npairs = n >> 1;
    const float inv_total = 1.0f / (float)n;

    // 2 pairs per thread, no loop: blocks = ceil(npairs / (2*NTHREADS))
    int blocks = (npairs + 2 * NTHREADS - 1) / (2 * NTHREADS);   // 8192 at B=8.4M

    if (ws_size >= (size_t)blocks * sizeof(float)) {
        float* partials = (float*)d_ws;
        crps_kernel<false><<<blocks, NTHREADS, 0, stream>>>(
            pp, tg, ag, ui, partials, npairs, inv_total);
        reduce_kernel<<<1, 1024, 0, stream>>>(partials, out, blocks, inv_total);
    } else {
        hipMemsetAsync(d_out, 0, sizeof(float), stream);
        crps_kernel<true><<<blocks, NTHREADS, 0, stream>>>(
            pp, tg, ag, ui, out, npairs, inv_total);
    }
}

// Round 8
// 174.983 us; speedup vs baseline: 1.0540x; 1.0060x over previous
//
#include <hip/hip_runtime.h>
#include <math.h>

// CRPS reduction kernel for MI355X (gfx950), round 8.
// Invariant across R2/R6/R7: VALU-busy time ~25us regardless of structure;
// total ~64us; HBM 16%; compiler clamps VGPR (20) and re-serializes ILP.
// This round: shrink the VALU work itself with packed fp32 (v_pk_fma_f32,
// gfx90a+). All element math rewritten on <2 x float> ext-vectors (the two
// elements of each float4 row-pair), using __builtin_elementwise_fma so FMA
// chains lower to packed ops. Trans ops (exp/log/rcp) stay per-component =
// two independent scalar chains for the scheduler to interleave.
//
//   d_in[0]: pred_params (B,2) f32  -> mu = [:,0], ls = [:,1]
//   d_in[1]: tgts        (B,2) f32  -> tte = [:,0], censor = [:,1]
//   d_in[2]: ages        (B,)  f32
//   d_in[3]: use_intvl   int scalar (device)
// Output: d_out[0] = sum(crps)/B  (f32 scalar)

#define AGE_MAX_F      120.0f
#define INV_SQRT_PI_F  0.5641895835477563f
#define INV_SQRT_2PI_F 0.3989422804014327f
#define SQRT_2PI_F     2.5066282746310002f
#define SQRT_2_F       1.4142135623730951f

#define NTHREADS 256

typedef float        v2  __attribute__((ext_vector_type(2)));
typedef unsigned int v2u __attribute__((ext_vector_type(2)));

__device__ __forceinline__ v2 v2fma(v2 a, v2 b, v2 c) {
    return __builtin_elementwise_fma(a, b, c);
}
__device__ __forceinline__ v2 expv(v2 x) {
    v2 r; r.x = __expf(x.x); r.y = __expf(x.y); return r;
}
__device__ __forceinline__ v2 logv(v2 x) {
    v2 r; r.x = __logf(x.x); r.y = __logf(x.y); return r;
}
__device__ __forceinline__ v2 rcpv(v2 x) {
    v2 r; r.x = __builtin_amdgcn_rcpf(x.x); r.y = __builtin_amdgcn_rcpf(x.y); return r;
}
__device__ __forceinline__ v2 absv(v2 x) {
    v2u u = __builtin_bit_cast(v2u, x) & 0x7fffffffu;
    return __builtin_bit_cast(v2, u);
}

// Phi(z) given phi = pdf(z), packed 2-wide. A&S 26.2.17, |err|<7.5e-8.
__device__ __forceinline__ v2 ndtrv(v2 z, v2 phi) {
    const v2 za = absv(z);
    const v2 t  = rcpv(v2fma((v2)0.2316419f, za, (v2)1.0f));
    v2 p = v2fma((v2)1.330274429f, t, (v2)-1.821255978f);
    p = v2fma(p, t, (v2)1.781477937f);
    p = v2fma(p, t, (v2)-0.356563782f);
    p = v2fma(p, t, (v2)0.319381530f);
    p = p * t;
    const v2 hm = v2fma(-phi, p, (v2)0.5f);        // Phi(|z|)-0.5
    // +-1.0 with z's sign bit, then c = sign*hm + 0.5
    const v2u sg = __builtin_bit_cast(v2u, z) & 0x80000000u;
    const v2  so = __builtin_bit_cast(v2, sg ^ __builtin_bit_cast(v2u, (v2)1.0f));
    return v2fma(so, hm, (v2)0.5f);
}

// Two elements (one float4 row-pair) at once, packed.
__device__ __forceinline__ v2 crps_pair(float4 pv, float4 tv, float2 av, int ui) {
    const v2 mu  = {pv.x, pv.z};
    const v2 ls  = {pv.y, pv.w};
    const v2 tte = {tv.x, tv.z};
    const v2 cen = {tv.y, tv.w};
    const v2 age = {av.x, av.y};

    const v2 h    = 0.5f * ls;
    const v2 s    = expv(h);           // sqrt(sigma2)
    const v2 invs = expv(-h);          // 1/sqrt(sigma2)
    const v2 Y    = logv(tte);

    const v2 dy   = Y - mu;
    const v2 z    = dy * invs;
    const v2 pdf  = expv(-0.5f * (z * z)) * INV_SQRT_2PI_F;
    const v2 c    = ndtrv(z, pdf);
    const v2 pdf2 = (pdf * pdf) * SQRT_2PI_F;      // phi(z*sqrt2)
    const v2 c2   = ndtrv(z * SQRT_2_F, pdf2);

    const v2 sp  = s * INV_SQRT_PI_F;
    const v2 tp  = (2.0f * s) * pdf;
    // IY  =  dy*c^2 + tp*c - sp*c2
    const v2 IY  = v2fma(dy * c, c, v2fma(tp, c, -(sp * c2)));
    const v2 omc = 1.0f - c;
    const v2 InY = v2fma(-(dy * omc), omc, v2fma(tp, omc, -(sp * (1.0f - c2))));

    if (ui) {
        const v2 T     = logv((v2)AGE_MAX_F - age);
        const v2 dt    = mu - T;                   // argument of I_(-T)
        const v2 zt    = dt * invs;
        const v2 pdft  = expv(-0.5f * (zt * zt)) * INV_SQRT_2PI_F;
        const v2 ct    = ndtrv(zt, pdft);
        const v2 pdft2 = (pdft * pdft) * SQRT_2PI_F;
        const v2 c2t   = ndtrv(zt * SQRT_2_F, pdft2);
        const v2 InT   = v2fma(dt * ct, ct, v2fma((2.0f * s) * ct, pdft, -(sp * c2t)));
        return IY + InT + (1.0f - cen) * (InY - InT);
    } else {
        return IY + (1.0f - cen) * InY;
    }
}

template <bool USE_ATOMIC>
__global__ __launch_bounds__(NTHREADS) void crps_kernel(
    const float4* __restrict__ pp,
    const float4* __restrict__ tg,
    const float2* __restrict__ ag,
    const int*    __restrict__ use_intvl_p,
    float*        __restrict__ partials,
    int npairs, float inv_total)
{
    const int half = gridDim.x * NTHREADS;
    const int i0   = blockIdx.x * NTHREADS + threadIdx.x;
    const int i1   = i0 + half;
    const int ui   = *use_intvl_p;

    v2 acc2 = (v2)0.0f;
    if (i0 < npairs) {
        const float4 p0 = pp[i0];
        const float4 t0 = tg[i0];
        const float2 a0 = ag[i0];
        if (i1 < npairs) {
            const float4 p1 = pp[i1];
            const float4 t1 = tg[i1];
            const float2 a1 = ag[i1];
            acc2 = crps_pair(p0, t0, a0, ui) + crps_pair(p1, t1, a1, ui);
        } else {
            acc2 = crps_pair(p0, t0, a0, ui);
        }
    }
    float acc = acc2.x + acc2.y;

    // wave64 shuffle reduce
    #pragma unroll
    for (int off = 32; off > 0; off >>= 1)
        acc += __shfl_down(acc, off);

    __shared__ float wsum[NTHREADS / 64];
    const int lane = threadIdx.x & 63;
    const int wid  = threadIdx.x >> 6;
    if (lane == 0) wsum[wid] = acc;
    __syncthreads();
    if (threadIdx.x == 0) {
        float blocksum = 0.0f;
        #pragma unroll
        for (int w = 0; w < NTHREADS / 64; ++w) blocksum += wsum[w];
        if (USE_ATOMIC) {
            atomicAdd(partials, blocksum * inv_total);
        } else {
            partials[blockIdx.x] = blocksum;
        }
    }
}

// Reduce nparts partials -> out[0] = sum * inv_total. One block of 1024.
__global__ __launch_bounds__(1024) void reduce_kernel(
    const float* __restrict__ partials,
    float* __restrict__ out, int nparts, float inv_total)
{
    float acc = 0.0f;
    for (int i = threadIdx.x; i < nparts; i += 1024)
        acc += partials[i];

    #pragma unroll
    for (int off = 32; off > 0; off >>= 1)
        acc += __shfl_down(acc, off);

    __shared__ float wsum[16];
    const int lane = threadIdx.x & 63;
    const int wid  = threadIdx.x >> 6;
    if (lane == 0) wsum[wid] = acc;
    __syncthreads();
    if (threadIdx.x == 0) {
        float s = 0.0f;
        #pragma unroll
        for (int w = 0; w < 16; ++w) s += wsum[w];
        out[0] = s * inv_total;
    }
}

extern "C" void kernel_launch(void* const* d_in, const int* in_sizes, int n_in,
                              void* d_out, int out_size, void* d_ws, size_t ws_size,
                              hipStream_t stream) {
    const float4* pp = (const float4*)d_in[0];
    const float4* tg = (const float4*)d_in[1];
    const float2* ag = (const float2*)d_in[2];
    const int*    ui = (const int*)d_in[3];
    float* out = (float*)d_out;

    const int n      = in_sizes[2];      // B
    const int npairs = n >> 1;
    const float inv_total = 1.0f / (float)n;

    int blocks = (npairs + 2 * NTHREADS - 1) / (2 * NTHREADS);   // 8192 at B=8.4M

    if (ws_size >= (size_t)blocks * sizeof(float)) {
        float* partials = (float*)d_ws;
        crps_kernel<false><<<blocks, NTHREADS, 0, stream>>>(
            pp, tg, ag, ui, partials, npairs, inv_total);
        reduce_kernel<<<1, 1024, 0, stream>>>(partials, out, blocks, inv_total);
    } else {
        hipMemsetAsync(d_out, 0, sizeof(float), stream);
        crps_kernel<true><<<blocks, NTHREADS, 0, stream>>>(
            pp, tg, ag, ui, out, npairs, inv_total);
    }
}